// Round 10
// baseline (8337.264 us; speedup 1.0000x reference)
//
#include <hip/hip_runtime.h>
#include <hip/hip_bf16.h>
#include <cfloat>
#include <math.h>

#define T_TOK 4096
#define H_DIM 2048
#define E_NUM 64
#define I_DIM 1024
#define TOPK  8
#define BM    256
#define BK    32
#define MAXT  192   // max Sum_e ceil(cnt_e/BM) = 32768/256 + 64 = 191

typedef __attribute__((ext_vector_type(4))) float f32x4;
typedef __attribute__((ext_vector_type(8))) short bf16x8;
typedef __attribute__((ext_vector_type(4))) int   i32x4;

__device__ __forceinline__ unsigned short f2bf(float f) {
    union { float f; unsigned int u; } v; v.f = f;
    unsigned int r = v.u + 0x7FFFu + ((v.u >> 16) & 1u);  // RNE
    return (unsigned short)(r >> 16);
}
__device__ __forceinline__ unsigned int pack2(float a, float b) {
    return (unsigned int)f2bf(a) | ((unsigned int)f2bf(b) << 16);
}
__device__ __forceinline__ float bf2f(unsigned short u) {
    union { unsigned int u; float f; } v; v.u = (unsigned int)u << 16; return v.f;
}
__device__ __forceinline__ int cvtpk(float lo, float hi) {
    int r; asm("v_cvt_pk_bf16_f32 %0, %1, %2" : "=v"(r) : "v"(lo), "v"(hi)); return r;
}
__device__ __forceinline__ void gload16(const void* g, void* l) {
    __builtin_amdgcn_global_load_lds((const __attribute__((address_space(1))) unsigned int*)g,
                                     (__attribute__((address_space(3))) unsigned int*)l, 16, 0, 0);
}
// T4 counted waits (rule #18: sched_barrier(0) after each)
#define WAIT_VM4 do { asm volatile("s_waitcnt vmcnt(4)" ::: "memory"); __builtin_amdgcn_sched_barrier(0); } while(0)
#define WAIT_VM0 do { asm volatile("s_waitcnt vmcnt(0)" ::: "memory"); __builtin_amdgcn_sched_barrier(0); } while(0)
#define WAIT_LGKM0 do { asm volatile("s_waitcnt lgkmcnt(0)" ::: "memory"); __builtin_amdgcn_sched_barrier(0); } while(0)
#define BAR __builtin_amdgcn_s_barrier()

// ---------------------------------------------------------------- router
__global__ __launch_bounds__(256)
void router_kernel(const float* __restrict__ x, const float* __restrict__ gw,
                   const float* __restrict__ gb, unsigned short* __restrict__ xb,
                   int* __restrict__ topk_idx, float* __restrict__ topk_w,
                   int* __restrict__ counts)
{
    const int t = blockIdx.x;
    const int tid = threadIdx.x;
    __shared__ float xs[H_DIM];
    __shared__ float logits[E_NUM];
    const float* xrow = x + (size_t)t * H_DIM;

    #pragma unroll
    for (int i = 0; i < 2; ++i) {
        int c = i * 1024 + tid * 4;
        f32x4 v = *(const f32x4*)(xrow + c);
        *(f32x4*)(xs + c) = v;
        uint2 pk; pk.x = pack2(v.x, v.y); pk.y = pack2(v.z, v.w);
        *(uint2*)(xb + (size_t)t * H_DIM + c) = pk;
    }
    __syncthreads();

    const int wave = tid >> 6, lane = tid & 63;
    for (int ee = 0; ee < 16; ++ee) {
        const int e = wave * 16 + ee;
        const float* g = gw + (size_t)e * H_DIM;
        float p = 0.f;
        #pragma unroll
        for (int i = 0; i < 8; ++i) {
            int c = (i * 64 + lane) * 4;
            f32x4 gv = *(const f32x4*)(g + c);
            f32x4 xv = *(const f32x4*)(xs + c);
            p += gv.x * xv.x + gv.y * xv.y + gv.z * xv.z + gv.w * xv.w;
        }
        #pragma unroll
        for (int s = 32; s > 0; s >>= 1) p += __shfl_xor(p, s, 64);
        if (lane == 0) logits[e] = p + gb[e];
    }
    __syncthreads();

    if (tid < 64) {
        float cur = logits[tid];
        float wv[TOPK]; int wi[TOPK];
        #pragma unroll
        for (int k = 0; k < TOPK; ++k) {
            float bv = cur; int bi = tid;
            #pragma unroll
            for (int s = 32; s > 0; s >>= 1) {
                float ov = __shfl_xor(bv, s, 64);
                int   oi = __shfl_xor(bi, s, 64);
                if (ov > bv || (ov == bv && oi < bi)) { bv = ov; bi = oi; }
            }
            wv[k] = bv; wi[k] = bi;
            if (tid == bi) cur = -FLT_MAX;
        }
        if (tid == 0) {
            float mx = wv[0], sum = 0.f, ex[TOPK];
            #pragma unroll
            for (int k = 0; k < TOPK; ++k) { ex[k] = expf(wv[k] - mx); sum += ex[k]; }
            #pragma unroll
            for (int k = 0; k < TOPK; ++k) {
                topk_idx[t * TOPK + k] = wi[k];
                topk_w[t * TOPK + k]   = ex[k] / sum;
                atomicAdd(&counts[wi[k]], 1);
            }
        }
    }
}

// ---------------------------------------------------------------- scan + tile list
__global__ void scan_kernel(const int* __restrict__ counts, int* __restrict__ offsets,
                            int* __restrict__ cursors, int* __restrict__ tiles,
                            int* __restrict__ ntiles)
{
    if (threadIdx.x == 0) {
        int acc = 0, nt = 0;
        for (int e = 0; e < E_NUM; ++e) {
            offsets[e] = acc; cursors[e] = acc;
            int c = counts[e];
            for (int m = 0; m * BM < c; ++m) tiles[nt++] = (e << 16) | m;
            acc += c;
        }
        *ntiles = nt;
    }
}

// ---------------------------------------------------------------- scatter assignments
__global__ void assign_kernel(const int* __restrict__ topk_idx, const float* __restrict__ topk_w,
                              int* __restrict__ cursors, int* __restrict__ tok_of,
                              int* __restrict__ pos_of)
{
    int i = blockIdx.x * 256 + threadIdx.x;
    if (i >= T_TOK * TOPK) return;
    int e = topk_idx[i];
    int pos = atomicAdd(&cursors[e], 1);
    tok_of[pos] = i >> 3;
    pos_of[i]   = pos;
}

// ---------------------------------------------------------------- GEMM1: 256 x (128h+128g), T4 counted-vmcnt pipeline
// 512 thr / 8 waves (2M x 4N); acc 128 AGPR; LDS 64 KB -> 2 blocks/CU.
// One raw barrier per K-step; 4 B-loads stay in flight across every barrier (vmcnt(4), never 0 mid-loop).
__global__ __launch_bounds__(512, 4)
void gemm1_kernel(const unsigned short* __restrict__ xb, const float* __restrict__ fc1,
                  const int* __restrict__ counts, const int* __restrict__ offsets,
                  const int* __restrict__ tok_of, const int* __restrict__ tiles,
                  const int* __restrict__ ntiles, unsigned short* __restrict__ a_all)
{
    const int ty = blockIdx.y;
    if (ty >= *ntiles) return;
    const int code = tiles[ty];
    const int e = code >> 16, m0 = (code & 0xffff) * BM;
    const int cnt = counts[e], off = offsets[e];
    const int pn0 = blockIdx.x * 128;            // pair-col strip
    const float* W = fc1 + (size_t)e * (size_t)(2 * I_DIM) * H_DIM;

    __shared__ unsigned short sA0[BM * BK], sA1[BM * BK];   // 16 KB each
    __shared__ unsigned short sB0[BM * BK], sB1[BM * BK];   // 16 KB each (128h+128g rows x 32K)

    const int tid = threadIdx.x;
    const int wid = tid >> 6, lane = tid & 63;

    // ---- A staging map: 64B rows, 4 slots of 16B, slot XOR (row&3); linear LDS dest (rule #21)
    const int l2 = lane >> 2;                    // 0..15
    const int sl = (lane & 3) ^ (l2 & 3);        // pre-swizzled K-chunk on the SOURCE
    const int ar0 = wid * 32 + l2;               // i=0 row
    const int ar1 = ar0 + 16;                    // i=1 row
    int am0 = m0 + ar0; if (am0 >= cnt) am0 = cnt - 1;
    int am1 = m0 + ar1; if (am1 >= cnt) am1 = cnt - 1;
    const unsigned short* aS0 = xb + (size_t)tok_of[off + am0] * H_DIM + sl * 8;
    const unsigned short* aS1 = xb + (size_t)tok_of[off + am1] * H_DIM + sl * 8;

    // ---- B staging map: thread -> (row, K-half of 16 f32)
    const int brow = tid >> 1, bsel = tid & 1;
    const int wrow = (brow < 128) ? (pn0 + brow) : (I_DIM + pn0 + (brow - 128));
    const float* bSrc = W + (size_t)wrow * H_DIM + bsel * 16;
    const int c0 = bsel * 2;
    const int wb0 = brow * 64 + ((c0     ^ (brow & 3)) * 16);
    const int wb1 = brow * 64 + (((c0+1) ^ (brow & 3)) * 16);

    f32x4 accH[8][2], accG[8][2];
    #pragma unroll
    for (int m = 0; m < 8; ++m)
        #pragma unroll
        for (int n = 0; n < 2; ++n) {
            accH[m][n] = (f32x4){0.f, 0.f, 0.f, 0.f};
            accG[m][n] = (f32x4){0.f, 0.f, 0.f, 0.f};
        }

    const int wm = (wid >> 2) * 128;
    const int wn = (wid & 3) * 32;
    const int fr = lane & 15;
    const int kg = lane >> 4;                    // K-chunk 0..3

    f32x4 brA[4], brB[4];                        // two named B-reg sets (rule #20)

    auto loadB = [&](f32x4* br, int k0) {        // 4 x global_load_dwordx4
        br[0] = *(const f32x4*)(bSrc + k0);
        br[1] = *(const f32x4*)(bSrc + k0 + 4);
        br[2] = *(const f32x4*)(bSrc + k0 + 8);
        br[3] = *(const f32x4*)(bSrc + k0 + 12);
    };
    auto issueA = [&](int k0, unsigned short* sA) {   // 2 x global_load_lds
        gload16(aS0 + k0, (char*)sA + wid * 2048);
        gload16(aS1 + k0, (char*)sA + wid * 2048 + 1024);
    };
    auto storeB = [&](unsigned short* sB, const f32x4* br) {
        i32x4 p0 = (i32x4){cvtpk(br[0].x, br[0].y), cvtpk(br[0].z, br[0].w),
                           cvtpk(br[1].x, br[1].y), cvtpk(br[1].z, br[1].w)};
        i32x4 p1 = (i32x4){cvtpk(br[2].x, br[2].y), cvtpk(br[2].z, br[2].w),
                           cvtpk(br[3].x, br[3].y), cvtpk(br[3].z, br[3].w)};
        *(i32x4*)((char*)sB + wb0) = p0;
        *(i32x4*)((char*)sB + wb1) = p1;
    };
    auto compute = [&](const unsigned short* sA, const unsigned short* sB) {
        bf16x8 af[8], bh[2], bg[2];
        #pragma unroll
        for (int m = 0; m < 8; ++m) {
            int row = wm + m * 16 + fr;
            af[m] = *(const bf16x8*)((const char*)sA + row * 64 + ((kg ^ (row & 3)) * 16));
        }
        #pragma unroll
        for (int n = 0; n < 2; ++n) {
            int rh = wn + n * 16 + fr;
            bh[n] = *(const bf16x8*)((const char*)sB + rh * 64 + ((kg ^ (rh & 3)) * 16));
            int rg = 128 + rh;
            bg[n] = *(const bf16x8*)((const char*)sB + rg * 64 + ((kg ^ (rg & 3)) * 16));
        }
        __builtin_amdgcn_s_setprio(1);
        #pragma unroll
        for (int m = 0; m < 8; ++m)
            #pragma unroll
            for (int n = 0; n < 2; ++n) {
                accH[m][n] = __builtin_amdgcn_mfma_f32_16x16x32_bf16(af[m], bh[n], accH[m][n], 0, 0, 0);
                accG[m][n] = __builtin_amdgcn_mfma_f32_16x16x32_bf16(af[m], bg[n], accG[m][n], 0, 0, 0);
            }
        __builtin_amdgcn_s_setprio(0);
    };

    const int NT = H_DIM / BK;                   // 64 (even)
    // prologue: queue = brB(1)[4] + brA(2)[4] in flight across first barrier
    loadB(brA, 0);
    issueA(0, sA0);
    loadB(brB, BK);
    WAIT_VM4;                                    // brA(0)+A(0) done; brB(1) flying
    storeB(sB0, brA);
    loadB(brA, 2 * BK);
    WAIT_LGKM0;
    BAR;

    #pragma unroll 1
    for (int t = 0; t < NT; t += 2) {
        // ---- even step t: compute sA0/sB0
        if (t + 1 < NT) issueA((t + 1) * BK, sA1);
        compute(sA0, sB0);
        if (t + 1 < NT) storeB(sB1, brB);        // B(t+1) -> sB1 (compiler waits brB regs)
        if (t + 3 < NT) { loadB(brB, (t + 3) * BK); WAIT_VM4; }  // brA(t+2)+A(t+1) done; brB flies
        else            { WAIT_VM0; }
        WAIT_LGKM0;
        BAR;
        // ---- odd step t+1: compute sA1/sB1
        if (t + 2 < NT) issueA((t + 2) * BK, sA0);
        compute(sA1, sB1);
        if (t + 2 < NT) storeB(sB0, brA);        // B(t+2) -> sB0
        if (t + 4 < NT) { loadB(brA, (t + 4) * BK); WAIT_VM4; }  // brB(t+3)+A(t+2) done; brA flies
        else            { WAIT_VM0; }
        WAIT_LGKM0;
        BAR;
    }

    #pragma unroll
    for (int m = 0; m < 8; ++m) {
        int rbase = wm + m * 16 + kg * 4;
        #pragma unroll
        for (int r = 0; r < 4; ++r) {
            int gm = m0 + rbase + r;
            if (gm < cnt) {
                size_t rowoff = (size_t)(off + gm) * I_DIM + pn0 + wn;
                #pragma unroll
                for (int n = 0; n < 2; ++n) {
                    float h = accH[m][n][r];
                    float g = accG[m][n][r];
                    float a = 0.5f * h * (1.f + erff(h * 0.70710678118f)) * (g + 1.f);
                    a_all[rowoff + n * 16 + fr] = f2bf(a);
                }
            }
        }
    }
}

// ---------------------------------------------------------------- GEMM2: 256 x 256, T4 counted-vmcnt pipeline
__global__ __launch_bounds__(512, 4)
void gemm2_kernel(const unsigned short* __restrict__ a_all, const float* __restrict__ fc2,
                  const int* __restrict__ counts, const int* __restrict__ offsets,
                  const int* __restrict__ tiles, const int* __restrict__ ntiles,
                  unsigned short* __restrict__ y)
{
    const int ty = blockIdx.y;
    if (ty >= *ntiles) return;
    const int code = tiles[ty];
    const int e = code >> 16, m0 = (code & 0xffff) * BM;
    const int cnt = counts[e], off = offsets[e];
    const int n0 = blockIdx.x * 256;
    const float* W = fc2 + (size_t)e * (size_t)H_DIM * I_DIM;

    __shared__ unsigned short sA0[BM * BK], sA1[BM * BK];
    __shared__ unsigned short sB0[BM * BK], sB1[BM * BK];

    const int tid = threadIdx.x;
    const int wid = tid >> 6, lane = tid & 63;

    const int l2 = lane >> 2;
    const int sl = (lane & 3) ^ (l2 & 3);
    const int ar0 = wid * 32 + l2;
    const int ar1 = ar0 + 16;
    int am0 = m0 + ar0; if (am0 >= cnt) am0 = cnt - 1;
    int am1 = m0 + ar1; if (am1 >= cnt) am1 = cnt - 1;
    const unsigned short* aS0 = a_all + (size_t)(off + am0) * I_DIM + sl * 8;
    const unsigned short* aS1 = a_all + (size_t)(off + am1) * I_DIM + sl * 8;

    const int brow = tid >> 1, bsel = tid & 1;
    const float* bSrc = W + (size_t)(n0 + brow) * I_DIM + bsel * 16;
    const int c0 = bsel * 2;
    const int wb0 = brow * 64 + ((c0     ^ (brow & 3)) * 16);
    const int wb1 = brow * 64 + (((c0+1) ^ (brow & 3)) * 16);

    f32x4 acc[8][4];
    #pragma unroll
    for (int m = 0; m < 8; ++m)
        #pragma unroll
        for (int n = 0; n < 4; ++n) acc[m][n] = (f32x4){0.f, 0.f, 0.f, 0.f};

    const int wm = (wid >> 2) * 128;
    const int wn = (wid & 3) * 64;
    const int fr = lane & 15;
    const int kg = lane >> 4;

    f32x4 brA[4], brB[4];

    auto loadB = [&](f32x4* br, int k0) {
        br[0] = *(const f32x4*)(bSrc + k0);
        br[1] = *(const f32x4*)(bSrc + k0 + 4);
        br[2] = *(const f32x4*)(bSrc + k0 + 8);
        br[3] = *(const f32x4*)(bSrc + k0 + 12);
    };
    auto issueA = [&](int k0, unsigned short* sA) {
        gload16(aS0 + k0, (char*)sA + wid * 2048);
        gload16(aS1 + k0, (char*)sA + wid * 2048 + 1024);
    };
    auto storeB = [&](unsigned short* sB, const f32x4* br) {
        i32x4 p0 = (i32x4){cvtpk(br[0].x, br[0].y), cvtpk(br[0].z, br[0].w),
                           cvtpk(br[1].x, br[1].y), cvtpk(br[1].z, br[1].w)};
        i32x4 p1 = (i32x4){cvtpk(br[2].x, br[2].y), cvtpk(br[2].z, br[2].w),
                           cvtpk(br[3].x, br[3].y), cvtpk(br[3].z, br[3].w)};
        *(i32x4*)((char*)sB + wb0) = p0;
        *(i32x4*)((char*)sB + wb1) = p1;
    };
    auto compute = [&](const unsigned short* sA, const unsigned short* sB) {
        bf16x8 af[8], bf[4];
        #pragma unroll
        for (int m = 0; m < 8; ++m) {
            int row = wm + m * 16 + fr;
            af[m] = *(const bf16x8*)((const char*)sA + row * 64 + ((kg ^ (row & 3)) * 16));
        }
        #pragma unroll
        for (int n = 0; n < 4; ++n) {
            int row = wn + n * 16 + fr;
            bf[n] = *(const bf16x8*)((const char*)sB + row * 64 + ((kg ^ (row & 3)) * 16));
        }
        __builtin_amdgcn_s_setprio(1);
        #pragma unroll
        for (int m = 0; m < 8; ++m)
            #pragma unroll
            for (int n = 0; n < 4; ++n)
                acc[m][n] = __builtin_amdgcn_mfma_f32_16x16x32_bf16(af[m], bf[n], acc[m][n], 0, 0, 0);
        __builtin_amdgcn_s_setprio(0);
    };

    const int NT = I_DIM / BK;                   // 32 (even)
    loadB(brA, 0);
    issueA(0, sA0);
    loadB(brB, BK);
    WAIT_VM4;
    storeB(sB0, brA);
    loadB(brA, 2 * BK);
    WAIT_LGKM0;
    BAR;

    #pragma unroll 1
    for (int t = 0; t < NT; t += 2) {
        if (t + 1 < NT) issueA((t + 1) * BK, sA1);
        compute(sA0, sB0);
        if (t + 1 < NT) storeB(sB1, brB);
        if (t + 3 < NT) { loadB(brB, (t + 3) * BK); WAIT_VM4; }
        else            { WAIT_VM0; }
        WAIT_LGKM0;
        BAR;
        if (t + 2 < NT) issueA((t + 2) * BK, sA0);
        compute(sA1, sB1);
        if (t + 2 < NT) storeB(sB0, brA);
        if (t + 4 < NT) { loadB(brA, (t + 4) * BK); WAIT_VM4; }
        else            { WAIT_VM0; }
        WAIT_LGKM0;
        BAR;
    }

    #pragma unroll
    for (int m = 0; m < 8; ++m) {
        int rbase = wm + m * 16 + kg * 4;
        #pragma unroll
        for (int r = 0; r < 4; ++r) {
            int gm = m0 + rbase + r;
            if (gm < cnt) {
                size_t rowoff = (size_t)(off + gm) * H_DIM + n0 + wn;
                #pragma unroll
                for (int n = 0; n < 4; ++n)
                    y[rowoff + n * 16 + fr] = f2bf(acc[m][n][r]);
            }
        }
    }
}

// ---------------------------------------------------------------- combine: out[t] = sum_k w_k * y[pos_k]
__global__ __launch_bounds__(256)
void combine_kernel(const unsigned short* __restrict__ y, const int* __restrict__ pos_of,
                    const float* __restrict__ topk_w, float* __restrict__ out)
{
    const int t = blockIdx.x;
    const int tid = threadIdx.x;
    __shared__ int   sp[TOPK];
    __shared__ float sw[TOPK];
    if (tid < TOPK) {
        sp[tid] = pos_of[t * TOPK + tid];
        sw[tid] = topk_w[t * TOPK + tid];
    }
    __syncthreads();

    const int c0 = tid * 8;
    float acc[8];
    #pragma unroll
    for (int j = 0; j < 8; ++j) acc[j] = 0.f;
    #pragma unroll
    for (int k = 0; k < TOPK; ++k) {
        const float w = sw[k];
        i32x4 v = *(const i32x4*)(y + (size_t)sp[k] * H_DIM + c0);
        const unsigned short* u = (const unsigned short*)&v;
        #pragma unroll
        for (int j = 0; j < 8; ++j) acc[j] += w * bf2f(u[j]);
    }
    float* orow = out + (size_t)t * H_DIM + c0;
    *(f32x4*)orow       = (f32x4){acc[0], acc[1], acc[2], acc[3]};
    *(f32x4*)(orow + 4) = (f32x4){acc[4], acc[5], acc[6], acc[7]};
}

// ---------------------------------------------------------------- launch
extern "C" void kernel_launch(void* const* d_in, const int* in_sizes, int n_in,
                              void* d_out, int out_size, void* d_ws, size_t ws_size,
                              hipStream_t stream)
{
    const float* x   = (const float*)d_in[0];
    const float* gw  = (const float*)d_in[1];
    const float* gb  = (const float*)d_in[2];
    const float* fc1 = (const float*)d_in[3];
    const float* fc2 = (const float*)d_in[4];
    float* out = (float*)d_out;

    char* ws = (char*)d_ws;
    size_t o = 0;
    auto alloc = [&](size_t b) { void* p = ws + o; o = (o + b + 255) & ~(size_t)255; return p; };
    unsigned short* xb     = (unsigned short*)alloc((size_t)T_TOK * H_DIM * 2);
    int*            tk_idx = (int*)  alloc((size_t)T_TOK * TOPK * 4);
    float*          tk_w   = (float*)alloc((size_t)T_TOK * TOPK * 4);
    int*            counts = (int*)  alloc(E_NUM * 4);
    int*            offs   = (int*)  alloc(E_NUM * 4);
    int*            curs   = (int*)  alloc(E_NUM * 4);
    int*            tiles  = (int*)  alloc(MAXT * 4);
    int*            ntiles = (int*)  alloc(4);
    int*            tok_of = (int*)  alloc((size_t)T_TOK * TOPK * 4);
    int*            pos_of = (int*)  alloc((size_t)T_TOK * TOPK * 4);
    unsigned short* a_all  = (unsigned short*)alloc((size_t)(T_TOK * TOPK + BM) * I_DIM * 2);
    unsigned short* yb     = (unsigned short*)alloc((size_t)(T_TOK * TOPK + BM) * H_DIM * 2);
    (void)ws_size;

    hipMemsetAsync(counts, 0, E_NUM * 4, stream);

    router_kernel<<<T_TOK, 256, 0, stream>>>(x, gw, gb, xb, tk_idx, tk_w, counts);
    scan_kernel<<<1, 64, 0, stream>>>(counts, offs, curs, tiles, ntiles);
    assign_kernel<<<(T_TOK * TOPK + 255) / 256, 256, 0, stream>>>(tk_idx, tk_w, curs, tok_of, pos_of);
    gemm1_kernel<<<dim3(I_DIM / 128, MAXT), 512, 0, stream>>>(xb, fc1, counts, offs, tok_of,
                                                              tiles, ntiles, a_all);
    gemm2_kernel<<<dim3(H_DIM / 256, MAXT), 512, 0, stream>>>(a_all, fc2, counts, offs,
                                                              tiles, ntiles, yb);
    combine_kernel<<<T_TOK, 256, 0, stream>>>(yb, pos_of, tk_w, out);
}

// Round 11
// 1312.503 us; speedup vs baseline: 6.3522x; 6.3522x over previous
//
#include <hip/hip_runtime.h>
#include <hip/hip_bf16.h>
#include <cfloat>
#include <math.h>

#define T_TOK 4096
#define H_DIM 2048
#define E_NUM 64
#define I_DIM 1024
#define TOPK  8
#define BM    256
#define BK    64
#define MAXT  192   // max Sum_e ceil(cnt_e/BM) = 32768/256 + 64 = 191

typedef __attribute__((ext_vector_type(4))) float f32x4;
typedef __attribute__((ext_vector_type(8))) short bf16x8;
typedef __attribute__((ext_vector_type(4))) int   i32x4;

__device__ __forceinline__ unsigned short f2bf(float f) {
    union { float f; unsigned int u; } v; v.f = f;
    unsigned int r = v.u + 0x7FFFu + ((v.u >> 16) & 1u);  // RNE
    return (unsigned short)(r >> 16);
}
__device__ __forceinline__ unsigned int pack2(float a, float b) {
    return (unsigned int)f2bf(a) | ((unsigned int)f2bf(b) << 16);
}
__device__ __forceinline__ float bf2f(unsigned short u) {
    union { unsigned int u; float f; } v; v.u = (unsigned int)u << 16; return v.f;
}
__device__ __forceinline__ int cvtpk(float lo, float hi) {
    int r; asm("v_cvt_pk_bf16_f32 %0, %1, %2" : "=v"(r) : "v"(lo), "v"(hi)); return r;
}
__device__ __forceinline__ void gload16(const void* g, void* l) {
    __builtin_amdgcn_global_load_lds((const __attribute__((address_space(1))) unsigned int*)g,
                                     (__attribute__((address_space(3))) unsigned int*)l, 16, 0, 0);
}
// T4 counted waits (rule #18: sched_barrier(0) after each)
#define WAIT_VM4   do { asm volatile("s_waitcnt vmcnt(4)" ::: "memory"); __builtin_amdgcn_sched_barrier(0); } while(0)
#define WAIT_VM8   do { asm volatile("s_waitcnt vmcnt(8)" ::: "memory"); __builtin_amdgcn_sched_barrier(0); } while(0)
#define WAIT_VM0   do { asm volatile("s_waitcnt vmcnt(0)" ::: "memory"); __builtin_amdgcn_sched_barrier(0); } while(0)
#define WAIT_LGKM0 do { asm volatile("s_waitcnt lgkmcnt(0)" ::: "memory"); __builtin_amdgcn_sched_barrier(0); } while(0)
#define BAR __builtin_amdgcn_s_barrier()

// ---------------------------------------------------------------- router
__global__ __launch_bounds__(256)
void router_kernel(const float* __restrict__ x, const float* __restrict__ gw,
                   const float* __restrict__ gb, unsigned short* __restrict__ xb,
                   int* __restrict__ topk_idx, float* __restrict__ topk_w,
                   int* __restrict__ counts)
{
    const int t = blockIdx.x;
    const int tid = threadIdx.x;
    __shared__ float xs[H_DIM];
    __shared__ float logits[E_NUM];
    const float* xrow = x + (size_t)t * H_DIM;

    #pragma unroll
    for (int i = 0; i < 2; ++i) {
        int c = i * 1024 + tid * 4;
        f32x4 v = *(const f32x4*)(xrow + c);
        *(f32x4*)(xs + c) = v;
        uint2 pk; pk.x = pack2(v.x, v.y); pk.y = pack2(v.z, v.w);
        *(uint2*)(xb + (size_t)t * H_DIM + c) = pk;
    }
    __syncthreads();

    const int wave = tid >> 6, lane = tid & 63;
    for (int ee = 0; ee < 16; ++ee) {
        const int e = wave * 16 + ee;
        const float* g = gw + (size_t)e * H_DIM;
        float p = 0.f;
        #pragma unroll
        for (int i = 0; i < 8; ++i) {
            int c = (i * 64 + lane) * 4;
            f32x4 gv = *(const f32x4*)(g + c);
            f32x4 xv = *(const f32x4*)(xs + c);
            p += gv.x * xv.x + gv.y * xv.y + gv.z * xv.z + gv.w * xv.w;
        }
        #pragma unroll
        for (int s = 32; s > 0; s >>= 1) p += __shfl_xor(p, s, 64);
        if (lane == 0) logits[e] = p + gb[e];
    }
    __syncthreads();

    if (tid < 64) {
        float cur = logits[tid];
        float wv[TOPK]; int wi[TOPK];
        #pragma unroll
        for (int k = 0; k < TOPK; ++k) {
            float bv = cur; int bi = tid;
            #pragma unroll
            for (int s = 32; s > 0; s >>= 1) {
                float ov = __shfl_xor(bv, s, 64);
                int   oi = __shfl_xor(bi, s, 64);
                if (ov > bv || (ov == bv && oi < bi)) { bv = ov; bi = oi; }
            }
            wv[k] = bv; wi[k] = bi;
            if (tid == bi) cur = -FLT_MAX;
        }
        if (tid == 0) {
            float mx = wv[0], sum = 0.f, ex[TOPK];
            #pragma unroll
            for (int k = 0; k < TOPK; ++k) { ex[k] = expf(wv[k] - mx); sum += ex[k]; }
            #pragma unroll
            for (int k = 0; k < TOPK; ++k) {
                topk_idx[t * TOPK + k] = wi[k];
                topk_w[t * TOPK + k]   = ex[k] / sum;
                atomicAdd(&counts[wi[k]], 1);
            }
        }
    }
}

// ---------------------------------------------------------------- scan + tile list
__global__ void scan_kernel(const int* __restrict__ counts, int* __restrict__ offsets,
                            int* __restrict__ cursors, int* __restrict__ tiles,
                            int* __restrict__ ntiles)
{
    if (threadIdx.x == 0) {
        int acc = 0, nt = 0;
        for (int e = 0; e < E_NUM; ++e) {
            offsets[e] = acc; cursors[e] = acc;
            int c = counts[e];
            for (int m = 0; m * BM < c; ++m) tiles[nt++] = (e << 16) | m;
            acc += c;
        }
        *ntiles = nt;
    }
}

// ---------------------------------------------------------------- scatter assignments
__global__ void assign_kernel(const int* __restrict__ topk_idx, const float* __restrict__ topk_w,
                              int* __restrict__ cursors, int* __restrict__ tok_of,
                              int* __restrict__ pos_of)
{
    int i = blockIdx.x * 256 + threadIdx.x;
    if (i >= T_TOK * TOPK) return;
    int e = topk_idx[i];
    int pos = atomicAdd(&cursors[e], 1);
    tok_of[pos] = i >> 3;
    pos_of[i]   = pos;
}

// ---------------------------------------------------------------- GEMM1: 256 x (128h+128g) fused GeGLU
// R9 geometry+maps (validated), NEW loop: ONE raw barrier per K-step, counted vmcnt.
// 8 B-loads stay in flight across every barrier; 4 A-glds fly under compute. vmcnt never 0 mid-loop.
__global__ __launch_bounds__(512, 1)
void gemm1_kernel(const unsigned short* __restrict__ xb, const float* __restrict__ fc1,
                  const int* __restrict__ counts, const int* __restrict__ offsets,
                  const int* __restrict__ tok_of, const int* __restrict__ tiles,
                  const int* __restrict__ ntiles, unsigned short* __restrict__ a_all)
{
    const int ty = blockIdx.y;
    if (ty >= *ntiles) return;
    const int code = tiles[ty];
    const int e = code >> 16, m0 = (code & 0xffff) * BM;
    const int cnt = counts[e], off = offsets[e];
    const int pn0 = blockIdx.x * 128;            // pair-col strip (8 strips)
    const float* W = fc1 + (size_t)e * (size_t)(2 * I_DIM) * H_DIM;

    __shared__ unsigned short sA[2][BM * BK];    // 2 x 32 KB
    __shared__ unsigned short sB[2][BM * BK];    // 2 x 32 KB (128h + 128g rows)
    __shared__ int sTok[BM];

    const int tid = threadIdx.x;
    if (tid < BM) {
        int m = m0 + tid;
        sTok[tid] = tok_of[off + (m < cnt ? m : cnt - 1)];
    }
    __syncthreads();

    const int wid = tid >> 6, lane = tid & 63;
    const int srow = tid >> 3, sch = tid & 7;    // A staging: 64 rows x 8 slots of 16B
    const int brow = tid >> 1, bhalf = tid & 1;  // B staging: 256 rows x 2 K-halves of 32 f32

    const unsigned short* aSrc[4];
    #pragma unroll
    for (int i = 0; i < 4; ++i) {
        int row = srow + 64 * i;                 // 0..255
        aSrc[i] = xb + (size_t)sTok[row] * H_DIM + (sch ^ (row & 7)) * 8;  // pre-swizzled src
    }
    const int wrow = (brow < 128) ? (pn0 + brow) : (I_DIM + pn0 + (brow - 128));
    const float* bSrc = W + (size_t)wrow * H_DIM + bhalf * 32;

    f32x4 accH[8][2], accG[8][2];
    #pragma unroll
    for (int m = 0; m < 8; ++m)
        #pragma unroll
        for (int n = 0; n < 2; ++n) {
            accH[m][n] = (f32x4){0.f, 0.f, 0.f, 0.f};
            accG[m][n] = (f32x4){0.f, 0.f, 0.f, 0.f};
        }

    const int wm = (wid >> 2) * 128;             // 2 M-groups of 128
    const int wn = (wid & 3) * 32;               // 4 pair-groups of 32
    const int fr = lane & 15;
    const int kg = lane >> 4;

    f32x4 br[8];                                 // single in-flight B set (32 VGPR)

    auto loadB = [&](int k0) {                   // 8 x global_load_dwordx4
        #pragma unroll
        for (int j = 0; j < 8; ++j) br[j] = *(const f32x4*)(bSrc + k0 + j * 4);
    };
    auto issueA = [&](int k0, int buf) {         // 4 x global_load_lds (linear dest, rule #21)
        #pragma unroll
        for (int i = 0; i < 4; ++i)
            gload16(aSrc[i] + k0, &sA[buf][i * 4096 + tid * 8]);
    };
    auto storeB = [&](int buf) {
        #pragma unroll
        for (int j = 0; j < 4; ++j) {
            i32x4 pk = (i32x4){cvtpk(br[2*j].x,   br[2*j].y),
                               cvtpk(br[2*j].z,   br[2*j].w),
                               cvtpk(br[2*j+1].x, br[2*j+1].y),
                               cvtpk(br[2*j+1].z, br[2*j+1].w)};
            int s = bhalf * 4 + j;
            *(i32x4*)((char*)sB[buf] + brow * 128 + ((s ^ (brow & 7)) * 16)) = pk;
        }
    };
    auto compute = [&](int buf) {
        #pragma unroll
        for (int kk = 0; kk < 2; ++kk) {
            bf16x8 af[8], bh[2], bg[2];
            #pragma unroll
            for (int m = 0; m < 8; ++m) {
                int row = wm + m * 16 + fr;
                af[m] = *(const bf16x8*)((const char*)sA[buf] +
                        row * 128 + (((kk * 4 + kg) ^ (row & 7)) * 16));
            }
            #pragma unroll
            for (int n = 0; n < 2; ++n) {
                int rh = wn + n * 16 + fr;
                bh[n] = *(const bf16x8*)((const char*)sB[buf] +
                        rh * 128 + (((kk * 4 + kg) ^ (rh & 7)) * 16));
                int rg = 128 + rh;
                bg[n] = *(const bf16x8*)((const char*)sB[buf] +
                        rg * 128 + (((kk * 4 + kg) ^ (rg & 7)) * 16));
            }
            __builtin_amdgcn_s_setprio(1);
            #pragma unroll
            for (int m = 0; m < 8; ++m)
                #pragma unroll
                for (int n = 0; n < 2; ++n) {
                    accH[m][n] = __builtin_amdgcn_mfma_f32_16x16x32_bf16(af[m], bh[n], accH[m][n], 0, 0, 0);
                    accG[m][n] = __builtin_amdgcn_mfma_f32_16x16x32_bf16(af[m], bg[n], accG[m][n], 0, 0, 0);
                }
            __builtin_amdgcn_s_setprio(0);
        }
    };

    const int NT = H_DIM / BK;                   // 32
    // prologue: establish steady state {sA[0],sB[0] valid; br=B(1); A(1) NOT yet issued}
    loadB(0);                                    // B(0): 8 outstanding
    issueA(0, 0);                                // A(0): +4
    WAIT_VM4;                                    // B(0) done; A(0) flying
    storeB(0);
    loadB(BK);                                   // B(1): 4A + 8B outstanding
    WAIT_VM8;                                    // A(0) done; B(1) flying
    WAIT_LGKM0;
    BAR;

    int cur = 0;
    #pragma unroll 1
    for (int t = 0; t < NT; ++t) {
        const bool n1 = (t + 1) < NT, n2 = (t + 2) < NT;
        if (n1) {
            issueA((t + 1) * BK, cur ^ 1);       // 8B(t+1) + 4A outstanding
            WAIT_VM4;                            // B(t+1) regs done; A flying
            storeB(cur ^ 1);
        }
        if (n2) loadB((t + 2) * BK);             // 4A + 8B(t+2)
        compute(cur);                            // loads fly under 128 MFMA
        if (n2)      { WAIT_VM8; }               // A(t+1) landed; 8 B stay in flight across barrier
        else if (n1) { WAIT_VM0; }               // tail: drain remaining A
        WAIT_LGKM0;                              // ds_writes visible
        BAR;                                     // single barrier per K-step
        cur ^= 1;
    }

    #pragma unroll
    for (int m = 0; m < 8; ++m) {
        int rbase = wm + m * 16 + kg * 4;
        #pragma unroll
        for (int r = 0; r < 4; ++r) {
            int gm = m0 + rbase + r;
            if (gm < cnt) {
                size_t rowoff = (size_t)(off + gm) * I_DIM + pn0 + wn;
                #pragma unroll
                for (int n = 0; n < 2; ++n) {
                    float h = accH[m][n][r];
                    float g = accG[m][n][r];
                    float a = 0.5f * h * (1.f + erff(h * 0.70710678118f)) * (g + 1.f);
                    a_all[rowoff + n * 16 + fr] = f2bf(a);
                }
            }
        }
    }
}

// ---------------------------------------------------------------- GEMM2: 256 x 256, counted-vmcnt single-barrier
__global__ __launch_bounds__(512, 1)
void gemm2_kernel(const unsigned short* __restrict__ a_all, const float* __restrict__ fc2,
                  const int* __restrict__ counts, const int* __restrict__ offsets,
                  const int* __restrict__ tiles, const int* __restrict__ ntiles,
                  unsigned short* __restrict__ y)
{
    const int ty = blockIdx.y;
    if (ty >= *ntiles) return;
    const int code = tiles[ty];
    const int e = code >> 16, m0 = (code & 0xffff) * BM;
    const int cnt = counts[e], off = offsets[e];
    const int n0 = blockIdx.x * 256;             // 8 strips
    const float* W = fc2 + (size_t)e * (size_t)H_DIM * I_DIM;

    __shared__ unsigned short sA[2][BM * BK];    // 2 x 32 KB
    __shared__ unsigned short sB[2][BM * BK];    // 2 x 32 KB

    const int tid = threadIdx.x;
    const int wid = tid >> 6, lane = tid & 63;
    const int srow = tid >> 3, sch = tid & 7;
    const int brow = tid >> 1, bhalf = tid & 1;

    const unsigned short* aSrc[4];
    #pragma unroll
    for (int i = 0; i < 4; ++i) {
        int row = srow + 64 * i;
        aSrc[i] = a_all + (size_t)(off + m0 + row) * I_DIM + (sch ^ (row & 7)) * 8;
    }
    const float* bSrc = W + (size_t)(n0 + brow) * I_DIM + bhalf * 32;

    f32x4 acc[8][4];
    #pragma unroll
    for (int m = 0; m < 8; ++m)
        #pragma unroll
        for (int n = 0; n < 4; ++n) acc[m][n] = (f32x4){0.f, 0.f, 0.f, 0.f};

    const int wm = (wid >> 2) * 128;
    const int wn = (wid & 3) * 64;
    const int fr = lane & 15;
    const int kg = lane >> 4;

    f32x4 br[8];

    auto loadB = [&](int k0) {
        #pragma unroll
        for (int j = 0; j < 8; ++j) br[j] = *(const f32x4*)(bSrc + k0 + j * 4);
    };
    auto issueA = [&](int k0, int buf) {
        #pragma unroll
        for (int i = 0; i < 4; ++i)
            gload16(aSrc[i] + k0, &sA[buf][i * 4096 + tid * 8]);
    };
    auto storeB = [&](int buf) {
        #pragma unroll
        for (int j = 0; j < 4; ++j) {
            i32x4 pk = (i32x4){cvtpk(br[2*j].x,   br[2*j].y),
                               cvtpk(br[2*j].z,   br[2*j].w),
                               cvtpk(br[2*j+1].x, br[2*j+1].y),
                               cvtpk(br[2*j+1].z, br[2*j+1].w)};
            int s = bhalf * 4 + j;
            *(i32x4*)((char*)sB[buf] + brow * 128 + ((s ^ (brow & 7)) * 16)) = pk;
        }
    };
    auto compute = [&](int buf) {
        #pragma unroll
        for (int kk = 0; kk < 2; ++kk) {
            bf16x8 af[8], bf[4];
            #pragma unroll
            for (int m = 0; m < 8; ++m) {
                int row = wm + m * 16 + fr;
                af[m] = *(const bf16x8*)((const char*)sA[buf] +
                        row * 128 + (((kk * 4 + kg) ^ (row & 7)) * 16));
            }
            #pragma unroll
            for (int n = 0; n < 4; ++n) {
                int row = wn + n * 16 + fr;
                bf[n] = *(const bf16x8*)((const char*)sB[buf] +
                        row * 128 + (((kk * 4 + kg) ^ (row & 7)) * 16));
            }
            __builtin_amdgcn_s_setprio(1);
            #pragma unroll
            for (int m = 0; m < 8; ++m)
                #pragma unroll
                for (int n = 0; n < 4; ++n)
                    acc[m][n] = __builtin_amdgcn_mfma_f32_16x16x32_bf16(af[m], bf[n], acc[m][n], 0, 0, 0);
            __builtin_amdgcn_s_setprio(0);
        }
    };

    const int NT = I_DIM / BK;                   // 16
    loadB(0);
    issueA(0, 0);
    WAIT_VM4;
    storeB(0);
    loadB(BK);
    WAIT_VM8;
    WAIT_LGKM0;
    BAR;

    int cur = 0;
    #pragma unroll 1
    for (int t = 0; t < NT; ++t) {
        const bool n1 = (t + 1) < NT, n2 = (t + 2) < NT;
        if (n1) {
            issueA((t + 1) * BK, cur ^ 1);
            WAIT_VM4;
            storeB(cur ^ 1);
        }
        if (n2) loadB((t + 2) * BK);
        compute(cur);
        if (n2)      { WAIT_VM8; }
        else if (n1) { WAIT_VM0; }
        WAIT_LGKM0;
        BAR;
        cur ^= 1;
    }

    #pragma unroll
    for (int m = 0; m < 8; ++m) {
        int rbase = wm + m * 16 + kg * 4;
        #pragma unroll
        for (int r = 0; r < 4; ++r) {
            int gm = m0 + rbase + r;
            if (gm < cnt) {
                size_t rowoff = (size_t)(off + gm) * H_DIM + n0 + wn;
                #pragma unroll
                for (int n = 0; n < 4; ++n)
                    y[rowoff + n * 16 + fr] = f2bf(acc[m][n][r]);
            }
        }
    }
}

// ---------------------------------------------------------------- combine: out[t] = sum_k w_k * y[pos_k]
__global__ __launch_bounds__(256)
void combine_kernel(const unsigned short* __restrict__ y, const int* __restrict__ pos_of,
                    const float* __restrict__ topk_w, float* __restrict__ out)
{
    const int t = blockIdx.x;
    const int tid = threadIdx.x;
    __shared__ int   sp[TOPK];
    __shared__ float sw[TOPK];
    if (tid < TOPK) {
        sp[tid] = pos_of[t * TOPK + tid];
        sw[tid] = topk_w[t * TOPK + tid];
    }
    __syncthreads();

    const int c0 = tid * 8;
    float acc[8];
    #pragma unroll
    for (int j = 0; j < 8; ++j) acc[j] = 0.f;
    #pragma unroll
    for (int k = 0; k < TOPK; ++k) {
        const float w = sw[k];
        i32x4 v = *(const i32x4*)(y + (size_t)sp[k] * H_DIM + c0);
        const unsigned short* u = (const unsigned short*)&v;
        #pragma unroll
        for (int j = 0; j < 8; ++j) acc[j] += w * bf2f(u[j]);
    }
    float* orow = out + (size_t)t * H_DIM + c0;
    *(f32x4*)orow       = (f32x4){acc[0], acc[1], acc[2], acc[3]};
    *(f32x4*)(orow + 4) = (f32x4){acc[4], acc[5], acc[6], acc[7]};
}

// ---------------------------------------------------------------- launch
extern "C" void kernel_launch(void* const* d_in, const int* in_sizes, int n_in,
                              void* d_out, int out_size, void* d_ws, size_t ws_size,
                              hipStream_t stream)
{
    const float* x   = (const float*)d_in[0];
    const float* gw  = (const float*)d_in[1];
    const float* gb  = (const float*)d_in[2];
    const float* fc1 = (const float*)d_in[3];
    const float* fc2 = (const float*)d_in[4];
    float* out = (float*)d_out;

    char* ws = (char*)d_ws;
    size_t o = 0;
    auto alloc = [&](size_t b) { void* p = ws + o; o = (o + b + 255) & ~(size_t)255; return p; };
    unsigned short* xb     = (unsigned short*)alloc((size_t)T_TOK * H_DIM * 2);
    int*            tk_idx = (int*)  alloc((size_t)T_TOK * TOPK * 4);
    float*          tk_w   = (float*)alloc((size_t)T_TOK * TOPK * 4);
    int*            counts = (int*)  alloc(E_NUM * 4);
    int*            offs   = (int*)  alloc(E_NUM * 4);
    int*            curs   = (int*)  alloc(E_NUM * 4);
    int*            tiles  = (int*)  alloc(MAXT * 4);
    int*            ntiles = (int*)  alloc(4);
    int*            tok_of = (int*)  alloc((size_t)T_TOK * TOPK * 4);
    int*            pos_of = (int*)  alloc((size_t)T_TOK * TOPK * 4);
    unsigned short* a_all  = (unsigned short*)alloc((size_t)(T_TOK * TOPK + BM) * I_DIM * 2);
    unsigned short* yb     = (unsigned short*)alloc((size_t)(T_TOK * TOPK + BM) * H_DIM * 2);
    (void)ws_size;

    hipMemsetAsync(counts, 0, E_NUM * 4, stream);

    router_kernel<<<T_TOK, 256, 0, stream>>>(x, gw, gb, xb, tk_idx, tk_w, counts);
    scan_kernel<<<1, 64, 0, stream>>>(counts, offs, curs, tiles, ntiles);
    assign_kernel<<<(T_TOK * TOPK + 255) / 256, 256, 0, stream>>>(tk_idx, tk_w, curs, tok_of, pos_of);
    gemm1_kernel<<<dim3(I_DIM / 128, MAXT), 512, 0, stream>>>(xb, fc1, counts, offs, tok_of,
                                                              tiles, ntiles, a_all);
    gemm2_kernel<<<dim3(H_DIM / 256, MAXT), 512, 0, stream>>>(a_all, fc2, counts, offs,
                                                              tiles, ntiles, yb);
    combine_kernel<<<T_TOK, 256, 0, stream>>>(yb, pos_of, tk_w, out);
}

// Round 12
// 1127.978 us; speedup vs baseline: 7.3913x; 1.1636x over previous
//
#include <hip/hip_runtime.h>
#include <hip/hip_bf16.h>
#include <cfloat>
#include <math.h>

#define T_TOK 4096
#define H_DIM 2048
#define E_NUM 64
#define I_DIM 1024
#define TOPK  8
#define BM    256
#define BK    32
#define MAXT  192   // max Sum_e ceil(cnt_e/BM) = 32768/256 + 64 = 191

typedef __attribute__((ext_vector_type(4))) float f32x4;
typedef __attribute__((ext_vector_type(8))) short bf16x8;
typedef __attribute__((ext_vector_type(4))) int   i32x4;

__device__ __forceinline__ unsigned short f2bf(float f) {
    union { float f; unsigned int u; } v; v.f = f;
    unsigned int r = v.u + 0x7FFFu + ((v.u >> 16) & 1u);  // RNE
    return (unsigned short)(r >> 16);
}
__device__ __forceinline__ unsigned int pack2(float a, float b) {
    return (unsigned int)f2bf(a) | ((unsigned int)f2bf(b) << 16);
}
__device__ __forceinline__ float bf2f(unsigned short u) {
    union { unsigned int u; float f; } v; v.u = (unsigned int)u << 16; return v.f;
}
__device__ __forceinline__ int cvtpk(float lo, float hi) {
    int r; asm("v_cvt_pk_bf16_f32 %0, %1, %2" : "=v"(r) : "v"(lo), "v"(hi)); return r;
}
__device__ __forceinline__ void gload16(const void* g, void* l) {
    __builtin_amdgcn_global_load_lds((const __attribute__((address_space(1))) unsigned int*)g,
                                     (__attribute__((address_space(3))) unsigned int*)l, 16, 0, 0);
}
// 64-B-row swizzle (4 slots of 16B): rows 0,4,8,12 get distinct slots; max 2-way bank alias (free, m136)
__device__ __forceinline__ int xr(int row) { return (row & 3) ^ ((row >> 2) & 3); }

// T4 counted waits (rule #18: sched_barrier(0) after each)
#define WAIT_VM4   do { asm volatile("s_waitcnt vmcnt(4)" ::: "memory"); __builtin_amdgcn_sched_barrier(0); } while(0)
#define WAIT_VM0   do { asm volatile("s_waitcnt vmcnt(0)" ::: "memory"); __builtin_amdgcn_sched_barrier(0); } while(0)
#define WAIT_LGKM0 do { asm volatile("s_waitcnt lgkmcnt(0)" ::: "memory"); __builtin_amdgcn_sched_barrier(0); } while(0)
#define BAR __builtin_amdgcn_s_barrier()

// ---------------------------------------------------------------- router
__global__ __launch_bounds__(256)
void router_kernel(const float* __restrict__ x, const float* __restrict__ gw,
                   const float* __restrict__ gb, unsigned short* __restrict__ xb,
                   int* __restrict__ topk_idx, float* __restrict__ topk_w,
                   int* __restrict__ counts)
{
    const int t = blockIdx.x;
    const int tid = threadIdx.x;
    __shared__ float xs[H_DIM];
    __shared__ float logits[E_NUM];
    const float* xrow = x + (size_t)t * H_DIM;

    #pragma unroll
    for (int i = 0; i < 2; ++i) {
        int c = i * 1024 + tid * 4;
        f32x4 v = *(const f32x4*)(xrow + c);
        *(f32x4*)(xs + c) = v;
        uint2 pk; pk.x = pack2(v.x, v.y); pk.y = pack2(v.z, v.w);
        *(uint2*)(xb + (size_t)t * H_DIM + c) = pk;
    }
    __syncthreads();

    const int wave = tid >> 6, lane = tid & 63;
    for (int ee = 0; ee < 16; ++ee) {
        const int e = wave * 16 + ee;
        const float* g = gw + (size_t)e * H_DIM;
        float p = 0.f;
        #pragma unroll
        for (int i = 0; i < 8; ++i) {
            int c = (i * 64 + lane) * 4;
            f32x4 gv = *(const f32x4*)(g + c);
            f32x4 xv = *(const f32x4*)(xs + c);
            p += gv.x * xv.x + gv.y * xv.y + gv.z * xv.z + gv.w * xv.w;
        }
        #pragma unroll
        for (int s = 32; s > 0; s >>= 1) p += __shfl_xor(p, s, 64);
        if (lane == 0) logits[e] = p + gb[e];
    }
    __syncthreads();

    if (tid < 64) {
        float cur = logits[tid];
        float wv[TOPK]; int wi[TOPK];
        #pragma unroll
        for (int k = 0; k < TOPK; ++k) {
            float bv = cur; int bi = tid;
            #pragma unroll
            for (int s = 32; s > 0; s >>= 1) {
                float ov = __shfl_xor(bv, s, 64);
                int   oi = __shfl_xor(bi, s, 64);
                if (ov > bv || (ov == bv && oi < bi)) { bv = ov; bi = oi; }
            }
            wv[k] = bv; wi[k] = bi;
            if (tid == bi) cur = -FLT_MAX;
        }
        if (tid == 0) {
            float mx = wv[0], sum = 0.f, ex[TOPK];
            #pragma unroll
            for (int k = 0; k < TOPK; ++k) { ex[k] = expf(wv[k] - mx); sum += ex[k]; }
            #pragma unroll
            for (int k = 0; k < TOPK; ++k) {
                topk_idx[t * TOPK + k] = wi[k];
                topk_w[t * TOPK + k]   = ex[k] / sum;
                atomicAdd(&counts[wi[k]], 1);
            }
        }
    }
}

// ---------------------------------------------------------------- scan + tile list
__global__ void scan_kernel(const int* __restrict__ counts, int* __restrict__ offsets,
                            int* __restrict__ cursors, int* __restrict__ tiles,
                            int* __restrict__ ntiles)
{
    if (threadIdx.x == 0) {
        int acc = 0, nt = 0;
        for (int e = 0; e < E_NUM; ++e) {
            offsets[e] = acc; cursors[e] = acc;
            int c = counts[e];
            for (int m = 0; m * BM < c; ++m) tiles[nt++] = (e << 16) | m;
            acc += c;
        }
        *ntiles = nt;
    }
}

// ---------------------------------------------------------------- scatter assignments
__global__ void assign_kernel(const int* __restrict__ topk_idx, const float* __restrict__ topk_w,
                              int* __restrict__ cursors, int* __restrict__ tok_of,
                              int* __restrict__ pos_of)
{
    int i = blockIdx.x * 256 + threadIdx.x;
    if (i >= T_TOK * TOPK) return;
    int e = topk_idx[i];
    int pos = atomicAdd(&cursors[e], 1);
    tok_of[pos] = i >> 3;
    pos_of[i]   = pos;
}

// ---------------------------------------------------------------- GEMM1: 256 x (64h+64g pairs), fused GeGLU
// 256 thr / 4 waves; acc 128 AGPR + ~110 VGPR -> 2 blocks/CU (the R7-proven 8 TB/s regime).
// BK=32, LDS 49 KB. R11's counted-vmcnt single-barrier loop: B(t+2) stays in flight across every barrier.
__global__ __launch_bounds__(256, 2)
void gemm1_kernel(const unsigned short* __restrict__ xb, const float* __restrict__ fc1,
                  const int* __restrict__ counts, const int* __restrict__ offsets,
                  const int* __restrict__ tok_of, const int* __restrict__ tiles,
                  const int* __restrict__ ntiles, unsigned short* __restrict__ a_all)
{
    const int ty = blockIdx.y;
    if (ty >= *ntiles) return;
    const int code = tiles[ty];
    const int e = code >> 16, m0 = (code & 0xffff) * BM;
    const int cnt = counts[e], off = offsets[e];
    const int pn0 = blockIdx.x * 64;             // 64-pair strip; 16 strips
    const float* W = fc1 + (size_t)e * (size_t)(2 * I_DIM) * H_DIM;

    __shared__ unsigned short sA[2][BM * BK];    // 2 x 16 KB
    __shared__ unsigned short sB[2][128 * BK];   // 2 x 8 KB (64 h rows + 64 g rows)
    __shared__ int sTok[BM];

    const int tid = threadIdx.x;
    sTok[tid] = tok_of[off + ((m0 + tid) < cnt ? (m0 + tid) : cnt - 1)];
    __syncthreads();

    const int wid = tid >> 6, lane = tid & 63;
    const int srow = tid >> 2, sch = tid & 3;    // A staging: 64 rows/pass x 4 slots of 16B
    const int brow = tid >> 1, bhalf = tid & 1;  // B staging: 128 rows x 2 K-halves of 16 f32

    const unsigned short* aSrc[4];
    #pragma unroll
    for (int i = 0; i < 4; ++i) {
        int row = srow + 64 * i;                 // 0..255
        aSrc[i] = xb + (size_t)sTok[row] * H_DIM + (sch ^ xr(row)) * 8;  // pre-swizzled src (rule #21)
    }
    const int wrow = (brow < 64) ? (pn0 + brow) : (I_DIM + pn0 + (brow - 64));
    const float* bSrc = W + (size_t)wrow * H_DIM + bhalf * 16;

    f32x4 accH[8][2], accG[8][2];
    #pragma unroll
    for (int m = 0; m < 8; ++m)
        #pragma unroll
        for (int n = 0; n < 2; ++n) {
            accH[m][n] = (f32x4){0.f, 0.f, 0.f, 0.f};
            accG[m][n] = (f32x4){0.f, 0.f, 0.f, 0.f};
        }

    const int wm = (wid >> 1) * 128;             // 2 M-groups of 128
    const int wnp = (wid & 1) * 32;              // 2 pair-groups of 32
    const int fr = lane & 15;
    const int kg = lane >> 4;                    // 16B K-chunk 0..3

    f32x4 br[4];                                 // 16 VGPR in-flight B

    auto loadB = [&](int k0) {                   // 4 x global_load_dwordx4
        #pragma unroll
        for (int j = 0; j < 4; ++j) br[j] = *(const f32x4*)(bSrc + k0 + j * 4);
    };
    auto issueA = [&](int k0, int buf) {         // 4 x global_load_lds, linear dest = tid*16B
        #pragma unroll
        for (int i = 0; i < 4; ++i)
            gload16(aSrc[i] + k0, &sA[buf][i * 2048 + tid * 8]);
    };
    auto storeB = [&](int buf) {
        #pragma unroll
        for (int j = 0; j < 2; ++j) {
            i32x4 pk = (i32x4){cvtpk(br[2*j].x,   br[2*j].y),
                               cvtpk(br[2*j].z,   br[2*j].w),
                               cvtpk(br[2*j+1].x, br[2*j+1].y),
                               cvtpk(br[2*j+1].z, br[2*j+1].w)};
            int s = bhalf * 2 + j;
            *(i32x4*)((char*)sB[buf] + brow * 64 + ((s ^ xr(brow)) * 16)) = pk;
        }
    };
    auto compute = [&](int buf) {
        bf16x8 af[8], bh[2], bg[2];
        #pragma unroll
        for (int m = 0; m < 8; ++m) {
            int row = wm + m * 16 + fr;
            af[m] = *(const bf16x8*)((const char*)sA[buf] + row * 64 + ((kg ^ xr(row)) * 16));
        }
        #pragma unroll
        for (int n = 0; n < 2; ++n) {
            int rh = wnp + n * 16 + fr;
            bh[n] = *(const bf16x8*)((const char*)sB[buf] + rh * 64 + ((kg ^ xr(rh)) * 16));
            int rg = 64 + rh;
            bg[n] = *(const bf16x8*)((const char*)sB[buf] + rg * 64 + ((kg ^ xr(rg)) * 16));
        }
        __builtin_amdgcn_s_setprio(1);
        #pragma unroll
        for (int m = 0; m < 8; ++m)
            #pragma unroll
            for (int n = 0; n < 2; ++n) {
                accH[m][n] = __builtin_amdgcn_mfma_f32_16x16x32_bf16(af[m], bh[n], accH[m][n], 0, 0, 0);
                accG[m][n] = __builtin_amdgcn_mfma_f32_16x16x32_bf16(af[m], bg[n], accG[m][n], 0, 0, 0);
            }
        __builtin_amdgcn_s_setprio(0);
    };

    const int NT = H_DIM / BK;                   // 64
    // prologue: steady state = {sA/sB[0] valid; br = B(1); 4 B-loads flying}
    loadB(0);                                    // 4 out
    issueA(0, 0);                                // 8 out
    WAIT_VM4;                                    // B(0) regs done; A(0) flying
    storeB(0);
    loadB(BK);                                   // 4A + 4B out
    WAIT_VM4;                                    // A(0) landed; B(1) flying
    WAIT_LGKM0;
    BAR;

    int cur = 0;
    #pragma unroll 1
    for (int t = 0; t < NT; ++t) {
        const bool n1 = (t + 1) < NT, n2 = (t + 2) < NT;
        if (n1) {
            issueA((t + 1) * BK, cur ^ 1);       // 4B(t+1) + 4A out
            WAIT_VM4;                            // B(t+1) regs done; A flying
            storeB(cur ^ 1);
        }
        if (n2) loadB((t + 2) * BK);             // 4A + 4B out
        compute(cur);                            // loads fly under 32 MFMA; 2nd block overlaps too
        if (n2)      { WAIT_VM4; }               // A(t+1) landed; B(t+2) stays in flight across barrier
        else if (n1) { WAIT_VM0; }
        WAIT_LGKM0;
        BAR;                                     // single barrier per K-step
        cur ^= 1;
    }

    #pragma unroll
    for (int m = 0; m < 8; ++m) {
        int rbase = wm + m * 16 + kg * 4;
        #pragma unroll
        for (int r = 0; r < 4; ++r) {
            int gm = m0 + rbase + r;
            if (gm < cnt) {
                size_t rowoff = (size_t)(off + gm) * I_DIM + pn0 + wnp;
                #pragma unroll
                for (int n = 0; n < 2; ++n) {
                    float h = accH[m][n][r];
                    float g = accG[m][n][r];
                    float a = 0.5f * h * (1.f + erff(h * 0.70710678118f)) * (g + 1.f);
                    a_all[rowoff + n * 16 + fr] = f2bf(a);
                }
            }
        }
    }
}

// ---------------------------------------------------------------- GEMM2: 256 x 128, 4 waves, counted-vmcnt
__global__ __launch_bounds__(256, 2)
void gemm2_kernel(const unsigned short* __restrict__ a_all, const float* __restrict__ fc2,
                  const int* __restrict__ counts, const int* __restrict__ offsets,
                  const int* __restrict__ tiles, const int* __restrict__ ntiles,
                  unsigned short* __restrict__ y)
{
    const int ty = blockIdx.y;
    if (ty >= *ntiles) return;
    const int code = tiles[ty];
    const int e = code >> 16, m0 = (code & 0xffff) * BM;
    const int cnt = counts[e], off = offsets[e];
    const int n0 = blockIdx.x * 128;             // 16 strips
    const float* W = fc2 + (size_t)e * (size_t)H_DIM * I_DIM;

    __shared__ unsigned short sA[2][BM * BK];    // 2 x 16 KB
    __shared__ unsigned short sB[2][128 * BK];   // 2 x 8 KB

    const int tid = threadIdx.x;
    const int wid = tid >> 6, lane = tid & 63;
    const int srow = tid >> 2, sch = tid & 3;
    const int brow = tid >> 1, bhalf = tid & 1;

    const unsigned short* aSrc[4];
    #pragma unroll
    for (int i = 0; i < 4; ++i) {
        int row = srow + 64 * i;
        aSrc[i] = a_all + (size_t)(off + m0 + row) * I_DIM + (sch ^ xr(row)) * 8;
    }
    const float* bSrc = W + (size_t)(n0 + brow) * I_DIM + bhalf * 16;

    f32x4 acc[8][4];
    #pragma unroll
    for (int m = 0; m < 8; ++m)
        #pragma unroll
        for (int n = 0; n < 4; ++n) acc[m][n] = (f32x4){0.f, 0.f, 0.f, 0.f};

    const int wm = (wid >> 1) * 128;             // 2 M-groups of 128
    const int wn = (wid & 1) * 64;               // 2 N-groups of 64
    const int fr = lane & 15;
    const int kg = lane >> 4;

    f32x4 br[4];

    auto loadB = [&](int k0) {
        #pragma unroll
        for (int j = 0; j < 4; ++j) br[j] = *(const f32x4*)(bSrc + k0 + j * 4);
    };
    auto issueA = [&](int k0, int buf) {
        #pragma unroll
        for (int i = 0; i < 4; ++i)
            gload16(aSrc[i] + k0, &sA[buf][i * 2048 + tid * 8]);
    };
    auto storeB = [&](int buf) {
        #pragma unroll
        for (int j = 0; j < 2; ++j) {
            i32x4 pk = (i32x4){cvtpk(br[2*j].x,   br[2*j].y),
                               cvtpk(br[2*j].z,   br[2*j].w),
                               cvtpk(br[2*j+1].x, br[2*j+1].y),
                               cvtpk(br[2*j+1].z, br[2*j+1].w)};
            int s = bhalf * 2 + j;
            *(i32x4*)((char*)sB[buf] + brow * 64 + ((s ^ xr(brow)) * 16)) = pk;
        }
    };
    auto compute = [&](int buf) {
        bf16x8 af[8], bf[4];
        #pragma unroll
        for (int m = 0; m < 8; ++m) {
            int row = wm + m * 16 + fr;
            af[m] = *(const bf16x8*)((const char*)sA[buf] + row * 64 + ((kg ^ xr(row)) * 16));
        }
        #pragma unroll
        for (int n = 0; n < 4; ++n) {
            int row = wn + n * 16 + fr;
            bf[n] = *(const bf16x8*)((const char*)sB[buf] + row * 64 + ((kg ^ xr(row)) * 16));
        }
        __builtin_amdgcn_s_setprio(1);
        #pragma unroll
        for (int m = 0; m < 8; ++m)
            #pragma unroll
            for (int n = 0; n < 4; ++n)
                acc[m][n] = __builtin_amdgcn_mfma_f32_16x16x32_bf16(af[m], bf[n], acc[m][n], 0, 0, 0);
        __builtin_amdgcn_s_setprio(0);
    };

    const int NT = I_DIM / BK;                   // 32
    loadB(0);
    issueA(0, 0);
    WAIT_VM4;
    storeB(0);
    loadB(BK);
    WAIT_VM4;
    WAIT_LGKM0;
    BAR;

    int cur = 0;
    #pragma unroll 1
    for (int t = 0; t < NT; ++t) {
        const bool n1 = (t + 1) < NT, n2 = (t + 2) < NT;
        if (n1) {
            issueA((t + 1) * BK, cur ^ 1);
            WAIT_VM4;
            storeB(cur ^ 1);
        }
        if (n2) loadB((t + 2) * BK);
        compute(cur);
        if (n2)      { WAIT_VM4; }
        else if (n1) { WAIT_VM0; }
        WAIT_LGKM0;
        BAR;
        cur ^= 1;
    }

    #pragma unroll
    for (int m = 0; m < 8; ++m) {
        int rbase = wm + m * 16 + kg * 4;
        #pragma unroll
        for (int r = 0; r < 4; ++r) {
            int gm = m0 + rbase + r;
            if (gm < cnt) {
                size_t rowoff = (size_t)(off + gm) * H_DIM + n0 + wn;
                #pragma unroll
                for (int n = 0; n < 4; ++n)
                    y[rowoff + n * 16 + fr] = f2bf(acc[m][n][r]);
            }
        }
    }
}

// ---------------------------------------------------------------- combine: out[t] = sum_k w_k * y[pos_k]
__global__ __launch_bounds__(256)
void combine_kernel(const unsigned short* __restrict__ y, const int* __restrict__ pos_of,
                    const float* __restrict__ topk_w, float* __restrict__ out)
{
    const int t = blockIdx.x;
    const int tid = threadIdx.x;
    __shared__ int   sp[TOPK];
    __shared__ float sw[TOPK];
    if (tid < TOPK) {
        sp[tid] = pos_of[t * TOPK + tid];
        sw[tid] = topk_w[t * TOPK + tid];
    }
    __syncthreads();

    const int c0 = tid * 8;
    float acc[8];
    #pragma unroll
    for (int j = 0; j < 8; ++j) acc[j] = 0.f;
    #pragma unroll
    for (int k = 0; k < TOPK; ++k) {
        const float w = sw[k];
        i32x4 v = *(const i32x4*)(y + (size_t)sp[k] * H_DIM + c0);
        const unsigned short* u = (const unsigned short*)&v;
        #pragma unroll
        for (int j = 0; j < 8; ++j) acc[j] += w * bf2f(u[j]);
    }
    float* orow = out + (size_t)t * H_DIM + c0;
    *(f32x4*)orow       = (f32x4){acc[0], acc[1], acc[2], acc[3]};
    *(f32x4*)(orow + 4) = (f32x4){acc[4], acc[5], acc[6], acc[7]};
}

// ---------------------------------------------------------------- launch
extern "C" void kernel_launch(void* const* d_in, const int* in_sizes, int n_in,
                              void* d_out, int out_size, void* d_ws, size_t ws_size,
                              hipStream_t stream)
{
    const float* x   = (const float*)d_in[0];
    const float* gw  = (const float*)d_in[1];
    const float* gb  = (const float*)d_in[2];
    const float* fc1 = (const float*)d_in[3];
    const float* fc2 = (const float*)d_in[4];
    float* out = (float*)d_out;

    char* ws = (char*)d_ws;
    size_t o = 0;
    auto alloc = [&](size_t b) { void* p = ws + o; o = (o + b + 255) & ~(size_t)255; return p; };
    unsigned short* xb     = (unsigned short*)alloc((size_t)T_TOK * H_DIM * 2);
    int*            tk_idx = (int*)  alloc((size_t)T_TOK * TOPK * 4);
    float*          tk_w   = (float*)alloc((size_t)T_TOK * TOPK * 4);
    int*            counts = (int*)  alloc(E_NUM * 4);
    int*            offs   = (int*)  alloc(E_NUM * 4);
    int*            curs   = (int*)  alloc(E_NUM * 4);
    int*            tiles  = (int*)  alloc(MAXT * 4);
    int*            ntiles = (int*)  alloc(4);
    int*            tok_of = (int*)  alloc((size_t)T_TOK * TOPK * 4);
    int*            pos_of = (int*)  alloc((size_t)T_TOK * TOPK * 4);
    unsigned short* a_all  = (unsigned short*)alloc((size_t)(T_TOK * TOPK + BM) * I_DIM * 2);
    unsigned short* yb     = (unsigned short*)alloc((size_t)(T_TOK * TOPK + BM) * H_DIM * 2);
    (void)ws_size;

    hipMemsetAsync(counts, 0, E_NUM * 4, stream);

    router_kernel<<<T_TOK, 256, 0, stream>>>(x, gw, gb, xb, tk_idx, tk_w, counts);
    scan_kernel<<<1, 64, 0, stream>>>(counts, offs, curs, tiles, ntiles);
    assign_kernel<<<(T_TOK * TOPK + 255) / 256, 256, 0, stream>>>(tk_idx, tk_w, curs, tok_of, pos_of);
    gemm1_kernel<<<dim3(I_DIM / 64, MAXT), 256, 0, stream>>>(xb, fc1, counts, offs, tok_of,
                                                             tiles, ntiles, a_all);
    gemm2_kernel<<<dim3(H_DIM / 128, MAXT), 256, 0, stream>>>(a_all, fc2, counts, offs,
                                                              tiles, ntiles, yb);
    combine_kernel<<<T_TOK, 256, 0, stream>>>(yb, pos_of, tk_w, out);
}